// Round 7
// baseline (282.360 us; speedup 1.0000x reference)
//
#include <hip/hip_runtime.h>
#include <stdint.h>

#define B_   128
#define N_   512
#define FIN  128
#define FOUT 64

using bf16x8 = __attribute__((ext_vector_type(8))) short;
using f32x4  = __attribute__((ext_vector_type(4))) float;

__device__ inline unsigned short f2bf(float x) {
    union { float f; uint32_t u; } c; c.f = x;
    uint32_t u = c.u;
    return (unsigned short)((u + 0x7FFFu + ((u >> 16) & 1u)) >> 16);  // RNE
}

// ---------------- kernel 1: h = X @ W via bf16 MFMA ----------------
// grid 512 = (b<<2)|quarter, 256 threads. W staged in LDS (16 KB); A-fragments
// loaded directly from global. Writes htT[b][f][j] bf16 + s,t fp32.
__global__ __launch_bounds__(256) void k_h(const float* __restrict__ X,
                                           const float* __restrict__ W,
                                           const float* __restrict__ a,
                                           uint16_t* __restrict__ htT,
                                           float* __restrict__ s,
                                           float* __restrict__ t) {
    __shared__ bf16x8 wl[16 * 64];   // W fragments: 4 ks x 4 nt, 16 KB

    const int b  = blockIdx.x >> 2;
    const int j0 = (blockIdx.x & 3) * 128;
    const int tid = threadIdx.x;
    const int w = tid >> 6, lane = tid & 63;
    const int q = lane >> 4, m = lane & 15;

    // ---- stage W fragments (ks = w): B[k][n], k=q*8+u, n=m ----
#pragma unroll
    for (int nt = 0; nt < 4; ++nt) {
        bf16x8 fr;
#pragma unroll
        for (int u = 0; u < 8; ++u)
            fr[u] = (short)f2bf(W[(w * 32 + q * 8 + u) * FOUT + nt * 16 + m]);
        wl[(w * 4 + nt) * 64 + lane] = fr;
    }
    __syncthreads();

    float asv[4], adv[4];
#pragma unroll
    for (int nt = 0; nt < 4; ++nt) {
        asv[nt] = a[nt * 16 + m];
        adv[nt] = a[FOUT + nt * 16 + m];
    }

    const float* xb = X + ((size_t)(b * N_) + j0) * FIN;

    for (int rl = 0; rl < 2; ++rl) {
        const int rt = w + rl * 4;
        const float* xrow = xb + (size_t)(rt * 16 + m) * FIN + q * 8;
        f32x4 acc[4] = {{0.f,0.f,0.f,0.f},{0.f,0.f,0.f,0.f},
                        {0.f,0.f,0.f,0.f},{0.f,0.f,0.f,0.f}};
#pragma unroll
        for (int ks = 0; ks < 4; ++ks) {
            float4 v0 = *(const float4*)(xrow + ks * 32);
            float4 v1 = *(const float4*)(xrow + ks * 32 + 4);
            bf16x8 af;
            af[0] = (short)f2bf(v0.x); af[1] = (short)f2bf(v0.y);
            af[2] = (short)f2bf(v0.z); af[3] = (short)f2bf(v0.w);
            af[4] = (short)f2bf(v1.x); af[5] = (short)f2bf(v1.y);
            af[6] = (short)f2bf(v1.z); af[7] = (short)f2bf(v1.w);
#pragma unroll
            for (int nt = 0; nt < 4; ++nt)
                acc[nt] = __builtin_amdgcn_mfma_f32_16x16x32_bf16(
                    af, wl[(ks * 4 + nt) * 64 + lane], acc[nt], 0, 0, 0);
        }

        // ---- s,t: per C-row dot with a_src/a_dst, reduce over m lanes ----
        float ps[4], pt[4];
#pragma unroll
        for (int r = 0; r < 4; ++r) {
            float vs = 0.f, vt = 0.f;
#pragma unroll
            for (int nt = 0; nt < 4; ++nt) {
                vs += acc[nt][r] * asv[nt];
                vt += acc[nt][r] * adv[nt];
            }
            vs += __shfl_xor(vs, 1, 64); vs += __shfl_xor(vs, 2, 64);
            vs += __shfl_xor(vs, 4, 64); vs += __shfl_xor(vs, 8, 64);
            vt += __shfl_xor(vt, 1, 64); vt += __shfl_xor(vt, 2, 64);
            vt += __shfl_xor(vt, 4, 64); vt += __shfl_xor(vt, 8, 64);
            ps[r] = vs; pt[r] = vt;
        }
        if (m < 4) {
            float vs = (m == 0) ? ps[0] : (m == 1) ? ps[1] : (m == 2) ? ps[2] : ps[3];
            float vt = (m == 0) ? pt[0] : (m == 1) ? pt[1] : (m == 2) ? pt[2] : pt[3];
            int row = j0 + rt * 16 + q * 4 + m;
            s[b * N_ + row] = vs;
            t[b * N_ + row] = vt;
        }

        // ---- store htT[b][f][j] bf16: C row=q*4+reg -> j, col=m -> f ----
#pragma unroll
        for (int nt = 0; nt < 4; ++nt) {
            uint32_t d0 = (uint32_t)f2bf(acc[nt][0]) | ((uint32_t)f2bf(acc[nt][1]) << 16);
            uint32_t d1 = (uint32_t)f2bf(acc[nt][2]) | ((uint32_t)f2bf(acc[nt][3]) << 16);
            uint2 dd; dd.x = d0; dd.y = d1;
            *(uint2*)(htT + (size_t)(b * FOUT + nt * 16 + m) * N_ + j0 + rt * 16 + q * 4) = dd;
        }
    }
}

// ---------------- kernel 2: attention + aggregation (bf16 MFMA) ----------------
// grid 512, bi = quarter*128 + b (same-b blocks -> same XCD -> htT L2-shared).
// 512 threads = 8 waves, one 16-row tile per wave.
// adj staged via fully-coalesced dword loads + __ballot into an 8 KB LDS
// bitmask -> the K-loop has ZERO global memory ops (pure LDS+VALU+MFMA).
// LDS 75 KB -> 2 blocks/CU -> 16 waves/CU = 4 waves/SIMD.
__global__ __launch_bounds__(512, 4) void k_attn(const int*    __restrict__ adj,
                                                 const uint16_t* __restrict__ htT,
                                                 const float*  __restrict__ s,
                                                 const float*  __restrict__ t,
                                                 float*        __restrict__ out) {
    __shared__ bf16x8   hstage[64 * 64];   // 64 KB, [pi=ks*4+nt][lane]
    __shared__ uint32_t lmask[128 * 18];   // 9 KB, row-stride 18 (bank-spread)
    __shared__ float    tsh[N_];           // 2 KB

    const int bi = blockIdx.x;
    const int b  = bi & 127;
    const int i0 = (bi >> 7) * 128;
    const int tid = threadIdx.x;          // 0..511
    const int w = tid >> 6, lane = tid & 63;
    const int q = lane >> 4, m = lane & 15;

    const uint16_t* hb = htT + (size_t)b * FOUT * N_;

    // ---- stage adj slab as bitmask: coalesced dword loads + ballot ----
    // wave w packs its own 16 rows; 256 B contiguous per load instruction.
    const int* arow_base = adj + ((size_t)(b * N_) + i0) * N_;
#pragma unroll 2
    for (int r = 0; r < 16; ++r) {
        const int row = w * 16 + r;
        const int* ap = arow_base + (size_t)row * N_;
#pragma unroll
        for (int it = 0; it < 8; ++it) {
            unsigned long long mb = __ballot(ap[it * 64 + lane] > 0);
            if (lane == 0) {
                lmask[row * 18 + it * 2]     = (uint32_t)mb;
                lmask[row * 18 + it * 2 + 1] = (uint32_t)(mb >> 32);
            }
        }
    }

    // ---- stage all of H[b] (64 KB) + t ----
#pragma unroll
    for (int i = 0; i < 8; ++i) {
        int pi = i * 8 + w, ks = pi >> 2, nt = pi & 3;
        hstage[pi * 64 + lane] =
            *(const bf16x8*)(hb + (size_t)(nt * 16 + m) * N_ + ks * 32 + q * 8);
    }
    tsh[tid] = t[b * N_ + tid];
    __syncthreads();

    const int irow = i0 + w * 16 + m;
    const float s_i = s[b * N_ + irow];
    const uint32_t* mymask = &lmask[(w * 16 + m) * 18];

    f32x4 acc[4] = {{0.f,0.f,0.f,0.f},{0.f,0.f,0.f,0.f},
                    {0.f,0.f,0.f,0.f},{0.f,0.f,0.f,0.f}};
    float lsum = 0.f;

#pragma unroll
    for (int ks = 0; ks < 16; ++ks) {
        const uint32_t word = mymask[ks];          // bits j = ks*32 .. +31
        const uint32_t bm = (word >> (q * 8)) & 0xffu;

        const int jb = ks * 32 + q * 8;
        float4 tj0 = *(const float4*)&tsh[jb];
        float4 tj1 = *(const float4*)&tsh[jb + 4];
        float tj[8] = {tj0.x, tj0.y, tj0.z, tj0.w, tj1.x, tj1.y, tj1.z, tj1.w};

        bf16x8 af;
#pragma unroll
        for (int u = 0; u < 8; ++u) {
            float e = s_i + tj[u];
            e = fmaxf(e, 0.2f * e);                // leaky_relu(e, 0.2)
            float p = (bm & (1u << u)) ? __expf(e) : 0.0f;
            lsum += p;
            af[u] = (short)f2bf(p);
        }

        bf16x8 bf0 = hstage[(ks * 4 + 0) * 64 + lane];
        bf16x8 bf1 = hstage[(ks * 4 + 1) * 64 + lane];
        bf16x8 bf2 = hstage[(ks * 4 + 2) * 64 + lane];
        bf16x8 bf3 = hstage[(ks * 4 + 3) * 64 + lane];

        acc[0] = __builtin_amdgcn_mfma_f32_16x16x32_bf16(af, bf0, acc[0], 0, 0, 0);
        acc[1] = __builtin_amdgcn_mfma_f32_16x16x32_bf16(af, bf1, acc[1], 0, 0, 0);
        acc[2] = __builtin_amdgcn_mfma_f32_16x16x32_bf16(af, bf2, acc[2], 0, 0, 0);
        acc[3] = __builtin_amdgcn_mfma_f32_16x16x32_bf16(af, bf3, acc[3], 0, 0, 0);
    }

    // row-sum l over q groups (lanes differ in bits 4,5)
    lsum += __shfl_xor(lsum, 16, 64);
    lsum += __shfl_xor(lsum, 32, 64);

#pragma unroll
    for (int reg = 0; reg < 4; ++reg) {
        float lr = __shfl(lsum, q * 4 + reg, 64);
        float inv = 1.0f / lr;
        int orow = i0 + w * 16 + q * 4 + reg;
        size_t ob = ((size_t)(b * N_) + orow) * FOUT + m;
#pragma unroll
        for (int nt = 0; nt < 4; ++nt) {
            float v = acc[nt][reg] * inv;
            v = fmaxf(v, 0.01f * v);
            out[ob + nt * 16] = v;
        }
    }
}

extern "C" void kernel_launch(void* const* d_in, const int* in_sizes, int n_in,
                              void* d_out, int out_size, void* d_ws, size_t ws_size,
                              hipStream_t stream) {
    const float* X   = (const float*)d_in[0];   // (B, N, FIN) fp32
    const int*   adj = (const int*)  d_in[1];   // (B, N, N) int32
    const float* W   = (const float*)d_in[2];   // (FIN, FOUT) fp32
    const float* a   = (const float*)d_in[3];   // (2*FOUT, 1) fp32
    float* out = (float*)d_out;                 // (B, N, FOUT) fp32

    uint16_t* htT = (uint16_t*)d_ws;                       // B*FOUT*N bf16 = 8 MB
    float* s = (float*)(htT + (size_t)B_ * FOUT * N_);     // 65536 floats
    float* t = s + B_ * N_;                                // 65536 floats

    k_h<<<B_ * 4, 256, 0, stream>>>(X, W, a, htT, s, t);
    k_attn<<<B_ * 4, 512, 0, stream>>>(adj, htT, s, t, out);
}

// Round 8
// 244.901 us; speedup vs baseline: 1.1530x; 1.1530x over previous
//
#include <hip/hip_runtime.h>
#include <stdint.h>

#define B_   128
#define N_   512
#define FIN  128
#define FOUT 64

using bf16x8 = __attribute__((ext_vector_type(8))) short;
using f32x4  = __attribute__((ext_vector_type(4))) float;

__device__ inline unsigned short f2bf(float x) {
    union { float f; uint32_t u; } c; c.f = x;
    uint32_t u = c.u;
    return (unsigned short)((u + 0x7FFFu + ((u >> 16) & 1u)) >> 16);  // RNE
}

// ---------------- kernel 0: adj -> bitmask, pure stream ----------------
// grid 1024x256 = 4096 waves; each wave packs a contiguous 32 KB span of adj
// with 16 coalesced dword loads in flight (4 KB/wave). Output 4 MB bitmask,
// flat: word g/32 holds bits of adj[g..g+31] (== [row][word16] layout).
__global__ __launch_bounds__(256) void k_pack(const int* __restrict__ adj,
                                              uint32_t* __restrict__ amask) {
    const int wid  = (blockIdx.x * 256 + threadIdx.x) >> 6;   // 0..4095
    const int lane = threadIdx.x & 63;
    const int* base = adj + (size_t)wid * 8192;               // 8 iters * 1024
    uint32_t* wout = amask + (size_t)wid * 256;

    for (int it = 0; it < 8; ++it) {
        const int* p = base + it * 1024;
        int v[16];
#pragma unroll
        for (int s = 0; s < 16; ++s) v[s] = p[s * 64 + lane];
        unsigned long long bb[16];
#pragma unroll
        for (int s = 0; s < 16; ++s) bb[s] = __ballot(v[s] > 0);
        if (lane == 0) {
#pragma unroll
            for (int k = 0; k < 8; ++k) {
                uint4 d;
                d.x = (uint32_t)bb[2 * k];     d.y = (uint32_t)(bb[2 * k] >> 32);
                d.z = (uint32_t)bb[2 * k + 1]; d.w = (uint32_t)(bb[2 * k + 1] >> 32);
                *(uint4*)(wout + it * 32 + k * 4) = d;
            }
        }
    }
}

// ---------------- kernel 1: h = X @ W via bf16 MFMA ----------------
// grid 512 = (b<<2)|quarter, 256 threads. W staged in LDS (16 KB); A-fragments
// loaded directly from global. Writes htT[b][f][j] bf16 + s,t fp32.
__global__ __launch_bounds__(256) void k_h(const float* __restrict__ X,
                                           const float* __restrict__ W,
                                           const float* __restrict__ a,
                                           uint16_t* __restrict__ htT,
                                           float* __restrict__ s,
                                           float* __restrict__ t) {
    __shared__ bf16x8 wl[16 * 64];   // W fragments: 4 ks x 4 nt, 16 KB

    const int b  = blockIdx.x >> 2;
    const int j0 = (blockIdx.x & 3) * 128;
    const int tid = threadIdx.x;
    const int w = tid >> 6, lane = tid & 63;
    const int q = lane >> 4, m = lane & 15;

    // ---- stage W fragments (ks = w): B[k][n], k=q*8+u, n=m ----
#pragma unroll
    for (int nt = 0; nt < 4; ++nt) {
        bf16x8 fr;
#pragma unroll
        for (int u = 0; u < 8; ++u)
            fr[u] = (short)f2bf(W[(w * 32 + q * 8 + u) * FOUT + nt * 16 + m]);
        wl[(w * 4 + nt) * 64 + lane] = fr;
    }
    __syncthreads();

    float asv[4], adv[4];
#pragma unroll
    for (int nt = 0; nt < 4; ++nt) {
        asv[nt] = a[nt * 16 + m];
        adv[nt] = a[FOUT + nt * 16 + m];
    }

    const float* xb = X + ((size_t)(b * N_) + j0) * FIN;

    for (int rl = 0; rl < 2; ++rl) {
        const int rt = w + rl * 4;
        const float* xrow = xb + (size_t)(rt * 16 + m) * FIN + q * 8;
        f32x4 acc[4] = {{0.f,0.f,0.f,0.f},{0.f,0.f,0.f,0.f},
                        {0.f,0.f,0.f,0.f},{0.f,0.f,0.f,0.f}};
#pragma unroll
        for (int ks = 0; ks < 4; ++ks) {
            float4 v0 = *(const float4*)(xrow + ks * 32);
            float4 v1 = *(const float4*)(xrow + ks * 32 + 4);
            bf16x8 af;
            af[0] = (short)f2bf(v0.x); af[1] = (short)f2bf(v0.y);
            af[2] = (short)f2bf(v0.z); af[3] = (short)f2bf(v0.w);
            af[4] = (short)f2bf(v1.x); af[5] = (short)f2bf(v1.y);
            af[6] = (short)f2bf(v1.z); af[7] = (short)f2bf(v1.w);
#pragma unroll
            for (int nt = 0; nt < 4; ++nt)
                acc[nt] = __builtin_amdgcn_mfma_f32_16x16x32_bf16(
                    af, wl[(ks * 4 + nt) * 64 + lane], acc[nt], 0, 0, 0);
        }

        // ---- s,t: per C-row dot with a_src/a_dst, reduce over m lanes ----
        float ps[4], pt[4];
#pragma unroll
        for (int r = 0; r < 4; ++r) {
            float vs = 0.f, vt = 0.f;
#pragma unroll
            for (int nt = 0; nt < 4; ++nt) {
                vs += acc[nt][r] * asv[nt];
                vt += acc[nt][r] * adv[nt];
            }
            vs += __shfl_xor(vs, 1, 64); vs += __shfl_xor(vs, 2, 64);
            vs += __shfl_xor(vs, 4, 64); vs += __shfl_xor(vs, 8, 64);
            vt += __shfl_xor(vt, 1, 64); vt += __shfl_xor(vt, 2, 64);
            vt += __shfl_xor(vt, 4, 64); vt += __shfl_xor(vt, 8, 64);
            ps[r] = vs; pt[r] = vt;
        }
        if (m < 4) {
            float vs = (m == 0) ? ps[0] : (m == 1) ? ps[1] : (m == 2) ? ps[2] : ps[3];
            float vt = (m == 0) ? pt[0] : (m == 1) ? pt[1] : (m == 2) ? pt[2] : pt[3];
            int row = j0 + rt * 16 + q * 4 + m;
            s[b * N_ + row] = vs;
            t[b * N_ + row] = vt;
        }

        // ---- store htT[b][f][j] bf16: C row=q*4+reg -> j, col=m -> f ----
#pragma unroll
        for (int nt = 0; nt < 4; ++nt) {
            uint32_t d0 = (uint32_t)f2bf(acc[nt][0]) | ((uint32_t)f2bf(acc[nt][1]) << 16);
            uint32_t d1 = (uint32_t)f2bf(acc[nt][2]) | ((uint32_t)f2bf(acc[nt][3]) << 16);
            uint2 dd; dd.x = d0; dd.y = d1;
            *(uint2*)(htT + (size_t)(b * FOUT + nt * 16 + m) * N_ + j0 + rt * 16 + q * 4) = dd;
        }
    }
}

// ---------------- kernel 2: attention + aggregation (bf16 MFMA) ----------------
// grid 512, bi = quarter*128 + b (same-b blocks -> same XCD -> htT L2-shared).
// 512 threads = 8 waves, one 16-row tile per wave. Each lane preloads its row's
// FULL 64-B adj bitmask into 4 int4 registers -> the K-loop has zero global
// memory ops and zero mask-LDS ops. LDS 66 KB -> 2 blocks/CU, 4 waves/SIMD.
__global__ __launch_bounds__(512, 4) void k_attn(const uint32_t* __restrict__ amask,
                                                 const uint16_t* __restrict__ htT,
                                                 const float*  __restrict__ s,
                                                 const float*  __restrict__ t,
                                                 float*        __restrict__ out) {
    __shared__ bf16x8 hstage[64 * 64];   // 64 KB, [pi=ks*4+nt][lane]
    __shared__ float  tsh[N_];           // 2 KB

    const int bi = blockIdx.x;
    const int b  = bi & 127;
    const int i0 = (bi >> 7) * 128;
    const int tid = threadIdx.x;          // 0..511
    const int w = tid >> 6, lane = tid & 63;
    const int q = lane >> 4, m = lane & 15;

    const uint16_t* hb = htT + (size_t)b * FOUT * N_;

    // ---- preload this lane's row mask: 16 words in 4 int4 (registers) ----
    const uint32_t* mrow = amask + ((size_t)(b * N_) + i0 + w * 16 + m) * 16;
    uint32_t mw[16];
    *(int4*)&mw[0]  = *(const int4*)(mrow);
    *(int4*)&mw[4]  = *(const int4*)(mrow + 4);
    *(int4*)&mw[8]  = *(const int4*)(mrow + 8);
    *(int4*)&mw[12] = *(const int4*)(mrow + 12);

    // ---- stage all of H[b] (64 KB) + t ----
#pragma unroll
    for (int i = 0; i < 8; ++i) {
        int pi = i * 8 + w, ks = pi >> 2, nt = pi & 3;
        hstage[pi * 64 + lane] =
            *(const bf16x8*)(hb + (size_t)(nt * 16 + m) * N_ + ks * 32 + q * 8);
    }
    tsh[tid] = t[b * N_ + tid];
    __syncthreads();

    const float s_i = s[b * N_ + i0 + w * 16 + m];

    f32x4 acc[4] = {{0.f,0.f,0.f,0.f},{0.f,0.f,0.f,0.f},
                    {0.f,0.f,0.f,0.f},{0.f,0.f,0.f,0.f}};
    float lsum = 0.f;

#pragma unroll
    for (int ks = 0; ks < 16; ++ks) {
        const uint32_t bm = (mw[ks] >> (q * 8)) & 0xffu;   // bits j=ks*32+q*8..+7

        const int jb = ks * 32 + q * 8;
        float4 tj0 = *(const float4*)&tsh[jb];
        float4 tj1 = *(const float4*)&tsh[jb + 4];
        float tj[8] = {tj0.x, tj0.y, tj0.z, tj0.w, tj1.x, tj1.y, tj1.z, tj1.w};

        bf16x8 af;
#pragma unroll
        for (int u = 0; u < 8; ++u) {
            float e = s_i + tj[u];
            e = fmaxf(e, 0.2f * e);                // leaky_relu(e, 0.2)
            float p = (bm & (1u << u)) ? __expf(e) : 0.0f;
            lsum += p;
            af[u] = (short)f2bf(p);
        }

        bf16x8 bf0 = hstage[(ks * 4 + 0) * 64 + lane];
        bf16x8 bf1 = hstage[(ks * 4 + 1) * 64 + lane];
        bf16x8 bf2 = hstage[(ks * 4 + 2) * 64 + lane];
        bf16x8 bf3 = hstage[(ks * 4 + 3) * 64 + lane];

        acc[0] = __builtin_amdgcn_mfma_f32_16x16x32_bf16(af, bf0, acc[0], 0, 0, 0);
        acc[1] = __builtin_amdgcn_mfma_f32_16x16x32_bf16(af, bf1, acc[1], 0, 0, 0);
        acc[2] = __builtin_amdgcn_mfma_f32_16x16x32_bf16(af, bf2, acc[2], 0, 0, 0);
        acc[3] = __builtin_amdgcn_mfma_f32_16x16x32_bf16(af, bf3, acc[3], 0, 0, 0);
    }

    // row-sum l over q groups (lanes differ in bits 4,5)
    lsum += __shfl_xor(lsum, 16, 64);
    lsum += __shfl_xor(lsum, 32, 64);

#pragma unroll
    for (int reg = 0; reg < 4; ++reg) {
        float lr = __shfl(lsum, q * 4 + reg, 64);
        float inv = 1.0f / lr;
        int orow = i0 + w * 16 + q * 4 + reg;
        size_t ob = ((size_t)(b * N_) + orow) * FOUT + m;
#pragma unroll
        for (int nt = 0; nt < 4; ++nt) {
            float v = acc[nt][reg] * inv;
            v = fmaxf(v, 0.01f * v);
            out[ob + nt * 16] = v;
        }
    }
}

extern "C" void kernel_launch(void* const* d_in, const int* in_sizes, int n_in,
                              void* d_out, int out_size, void* d_ws, size_t ws_size,
                              hipStream_t stream) {
    const float* X   = (const float*)d_in[0];   // (B, N, FIN) fp32
    const int*   adj = (const int*)  d_in[1];   // (B, N, N) int32
    const float* W   = (const float*)d_in[2];   // (FIN, FOUT) fp32
    const float* a   = (const float*)d_in[3];   // (2*FOUT, 1) fp32
    float* out = (float*)d_out;                 // (B, N, FOUT) fp32

    uint16_t* htT = (uint16_t*)d_ws;                       // 8 MB
    float* s = (float*)(htT + (size_t)B_ * FOUT * N_);     // 256 KB
    float* t = s + B_ * N_;                                // 256 KB
    uint32_t* amask = (uint32_t*)(t + B_ * N_);            // 4 MB

    k_pack<<<1024, 256, 0, stream>>>(adj, amask);
    k_h<<<B_ * 4, 256, 0, stream>>>(X, W, a, htT, s, t);
    k_attn<<<B_ * 4, 512, 0, stream>>>(amask, htT, s, t, out);
}